// Round 1
// baseline (849.181 us; speedup 1.0000x reference)
//
#include <hip/hip_runtime.h>
#include <hip/hip_bf16.h>
#include <stdint.h>

#define SS 4096
#define TT 16
#define DD 512
#define NN 200000
#define EPSV 1e-7f

// ---- ws layout (4-byte units) ----
#define W_MODE    0   // 0=int32 bools, 1=byte bools, 2=float bools
#define W_NS      1   // num_sample
#define W_K       2
#define W_CUT     3   // u* (ordered-uint bits of cutoff value)
#define W_NEQ     4   // rank within equal group (r3)
#define W_CANDC   5
#define W_EQC     6
#define W_P1      7
#define W_R1      8
#define W_P20     9
#define W_R2      10
#define W_Z       12  // float
#define W_HIST    16  // 4096 bins
#define W_PADCNT  4112
#define W_FIRSTPAD 4128
#define W_NODECNT 4144
#define W_CNT     4160
#define W_SRCOFF  4176
#define W_CAND    4192  // 1024
#define W_EQ      5216  // 128
#define W_SIDX    5344  // 1024
#define W_SORIG   6368  // 1024 floats
#define W_SSCALE  7392  // 1024 floats

__device__ __forceinline__ unsigned ordkey(float s) {
    unsigned b = __float_as_uint(s);
    return (b & 0x80000000u) ? ~b : (b | 0x80000000u);
}

// K0: detect bool encoding, zero ws control+hist, per-row padcount/first_pad/nodecnt, num_sample
__global__ void __launch_bounds__(1024) k_init_stats(const int* pm, const float* nids,
                                                     int* wsi, float* wsf) {
    __shared__ int s_mode;
    int tid = threadIdx.x;
    for (int i = tid; i < W_HIST + 4096; i += 1024) wsi[i] = 0;
    if (tid == 0) s_mode = 0;
    __syncthreads();
    int m = 0;
    for (int i = tid; i < 16384; i += 1024) {       // 65536 bytes: safe for all encodings
        unsigned v = (unsigned)pm[i];
        if (v == 0x3F800000u) m |= 2;
        else if (v > 1u) m |= 1;
    }
    if (m) atomicOr(&s_mode, m);
    __syncthreads();
    int mode = (s_mode & 2) ? 2 : ((s_mode & 1) ? 1 : 0);

    int row = tid >> 6;   // 16 rows x 64 lanes (one wave each)
    int lane = tid & 63;
    const unsigned char* pmb = (const unsigned char*)pm;
    const float* pmf = (const float*)pm;
    int pcnt = 0, ncnt = 0;
    for (int s = lane; s < SS; s += 64) {
        int e = row * SS + s;
        bool p;
        if (mode == 1)      p = pmb[e] != 0;
        else if (mode == 2) p = pmf[e] != 0.0f;
        else                p = pm[e] != 0;
        pcnt += p ? 1 : 0;
        ncnt += (nids[e] != -1.0f) ? 1 : 0;
    }
    for (int off = 32; off; off >>= 1) {
        pcnt += __shfl_down(pcnt, off);
        ncnt += __shfl_down(ncnt, off);
    }
    if (lane == 0) {
        wsi[W_PADCNT + row] = pcnt;
        wsi[W_FIRSTPAD + row] = SS - pcnt;
        wsi[W_NODECNT + row] = ncnt;
    }
    __syncthreads();
    if (tid == 0) {
        int ns = 0;
        for (int t = 0; t < TT; t++) ns = max(ns, wsi[W_PADCNT + t]);
        wsi[W_NS] = ns;
        wsi[W_MODE] = mode;
    }
}

// K1: Z = sum(exp(w+g))
__global__ void k_sumexp(const float* __restrict__ w, const float* __restrict__ g, float* Z) {
    __shared__ float part[256];
    int gid = blockIdx.x * blockDim.x + threadIdx.x;
    int stride = gridDim.x * blockDim.x;
    float acc = 0.f;
    for (int i = gid; i < NN; i += stride) acc += expf(w[i] + g[i]);
    part[threadIdx.x] = acc;
    __syncthreads();
    for (int off = 128; off; off >>= 1) {
        if (threadIdx.x < off) part[threadIdx.x] += part[threadIdx.x + off];
        __syncthreads();
    }
    if (threadIdx.x == 0) atomicAdd(Z, part[0]);
}

// histogram passes over ordered-uint bits of s
__global__ void k_hist(const float* __restrict__ w, const float* __restrict__ g,
                       int* wsi, int level) {
    __shared__ int h[4096];
    int nb = (level == 2) ? 4096 : 1024;
    for (int i = threadIdx.x; i < nb; i += blockDim.x) h[i] = 0;
    __syncthreads();
    unsigned p1 = (unsigned)wsi[W_P1];
    unsigned p20 = (unsigned)wsi[W_P20];
    int gid = blockIdx.x * blockDim.x + threadIdx.x;
    int stride = gridDim.x * blockDim.x;
    for (int i = gid; i < NN; i += stride) {
        unsigned u = ordkey(w[i] + g[i]);
        if (level == 0) atomicAdd(&h[u >> 22], 1);
        else if (level == 1) { if ((u >> 22) == p1) atomicAdd(&h[(u >> 12) & 1023u], 1); }
        else                 { if ((u >> 12) == p20) atomicAdd(&h[u & 4095u], 1); }
    }
    __syncthreads();
    for (int i = threadIdx.x; i < nb; i += blockDim.x)
        if (h[i]) atomicAdd(&wsi[W_HIST + i], h[i]);
}

// tiny scan: find bin containing the target-th largest, then zero hist for next pass
__global__ void __launch_bounds__(1024) k_scan(int* wsi, int level) {
    if (threadIdx.x == 0) {
        int target = (level == 0) ? wsi[W_NS] : ((level == 1) ? wsi[W_R1] : wsi[W_R2]);
        int nb = (level == 2) ? 4096 : 1024;
        int cum = 0, b = nb - 1;
        for (; b > 0; b--) {
            int c = wsi[W_HIST + b];
            if (cum + c >= target) break;
            cum += c;
        }
        int r = target - cum;
        if (level == 0)      { wsi[W_P1] = b; wsi[W_R1] = r; }
        else if (level == 1) { wsi[W_P20] = (wsi[W_P1] << 10) | b; wsi[W_R2] = r; }
        else {
            wsi[W_CUT] = (int)((((unsigned)wsi[W_P20]) << 12) | (unsigned)b);
            wsi[W_NEQ] = r;
            wsi[W_CANDC] = 0; wsi[W_EQC] = 0;
        }
    }
    __syncthreads();
    for (int i = threadIdx.x; i < 4096; i += blockDim.x) wsi[W_HIST + i] = 0;
}

// collect indices with u > u* and u == u*
__global__ void k_collect(const float* __restrict__ w, const float* __restrict__ g, int* wsi) {
    unsigned cut = (unsigned)wsi[W_CUT];
    int gid = blockIdx.x * blockDim.x + threadIdx.x;
    int stride = gridDim.x * blockDim.x;
    for (int i = gid; i < NN; i += stride) {
        unsigned u = ordkey(w[i] + g[i]);
        if (u > cut) {
            int p = atomicAdd(&wsi[W_CANDC], 1);
            if (p < 1024) wsi[W_CAND + p] = i;
        } else if (u == cut) {
            int p = atomicAdd(&wsi[W_EQC], 1);
            if (p < 128) wsi[W_EQ + p] = i;
        }
    }
}

// single-block: bitonic sort (value desc, index asc), EPS prefix -> K, per-row counts, new_node_num
__global__ void __launch_bounds__(1024) k_finalize(const float* __restrict__ w,
                                                   const float* __restrict__ g,
                                                   const int* __restrict__ subn,
                                                   int* wsi, float* wsf, float* out_nnn) {
    __shared__ unsigned long long keys[1024];
    __shared__ int s_K;
    int tid = threadIdx.x;
    int cc = min(wsi[W_CANDC], 1024);
    int ec = min(wsi[W_EQC], 128);
    int ns = wsi[W_NS];
    unsigned long long key = 0xFFFFFFFFFFFFFFFFull;
    int idx = -1;
    if (tid < cc) idx = wsi[W_CAND + tid];
    else if (tid < cc + ec) idx = wsi[W_EQ + (tid - cc)];
    if (idx >= 0) {
        unsigned u = ordkey(w[idx] + g[idx]);
        key = (((unsigned long long)(u ^ 0xFFFFFFFFu)) << 32) | (unsigned)idx;  // asc key = val desc, idx asc
    }
    keys[tid] = key;
    if (tid == 0) s_K = 0;
    __syncthreads();
    for (int k = 2; k <= 1024; k <<= 1)
        for (int j = k >> 1; j > 0; j >>= 1) {
            int ixj = tid ^ j;
            if (ixj > tid) {
                unsigned long long a = keys[tid], b = keys[ixj];
                bool up = ((tid & k) == 0);
                if (up ? (a > b) : (a < b)) { keys[tid] = b; keys[ixj] = a; }
            }
            __syncthreads();
        }
    float Z = wsf[W_Z];
    int myidx = -1; float val = 0.f;
    if (tid < ns) {
        myidx = (int)(unsigned)(keys[tid] & 0xFFFFFFFFull);
        val = expf(w[myidx] + g[myidx]) / Z;
        if (val > EPSV) atomicAdd(&s_K, 1);
    }
    __syncthreads();
    int K = s_K;   // vals sorted desc -> keep is a prefix of length K
    if (tid < K) {
        wsi[W_SIDX + tid] = myidx;
        wsf[W_SORIG + tid] = (float)subn[myidx];
        wsf[W_SSCALE + tid] = val;
    }
    if (tid == 0) wsi[W_K] = K;
    if (tid < TT) {
        int pc = wsi[W_PADCNT + tid];
        int cnt = min(K, pc);
        wsi[W_CNT + tid] = cnt;
        wsi[W_SRCOFF + tid] = K - cnt;
        out_nnn[tid] = (float)(wsi[W_NODECNT + tid] + cnt);
    }
}

// small outputs: nids_new, padded_node_mask_new, padding_mask_new (all float)
__global__ void k_small(const float* __restrict__ nids, const int* __restrict__ wsi,
                        const float* __restrict__ wsf,
                        float* out_nids, float* out_nm, float* out_pm) {
    int e = blockIdx.x * blockDim.x + threadIdx.x;
    if (e >= TT * SS) return;
    int t = e >> 12, s = e & (SS - 1);
    int fp = wsi[W_FIRSTPAD + t];
    int cnt = wsi[W_CNT + t];
    bool within = (s >= fp) && (s < fp + cnt);
    out_nids[e] = within ? wsf[W_SORIG + wsi[W_SRCOFF + t] + (s - fp)] : nids[e];
    out_nm[e] = ((s < wsi[W_NODECNT + t]) || within) ? 1.0f : 0.0f;
    out_pm[e] = ((s >= fp) && !within) ? 1.0f : 0.0f;
}

// big output: new_x in (S,T,D); copy or scatter scaled node_data rows
__global__ void __launch_bounds__(128) k_x(const float* __restrict__ x,
                                           const float* __restrict__ nd,
                                           const int* __restrict__ wsi,
                                           const float* __restrict__ wsf,
                                           float* __restrict__ out) {
    int rid = blockIdx.x;        // rid = s*T + t
    int t = rid & (TT - 1);
    int s = rid >> 4;
    int fp = wsi[W_FIRSTPAD + t];
    int cnt = wsi[W_CNT + t];
    int d4 = threadIdx.x;        // 128 float4 = 512 floats
    float4* o = (float4*)(out + (size_t)rid * DD);
    if (s >= fp && s < fp + cnt) {
        int j = wsi[W_SRCOFF + t] + (s - fp);
        int row = wsi[W_SIDX + j];
        float sc = wsf[W_SSCALE + j];
        float4 v = ((const float4*)(nd + (size_t)row * DD))[d4];
        v.x *= sc; v.y *= sc; v.z *= sc; v.w *= sc;
        o[d4] = v;
    } else {
        o[d4] = ((const float4*)(x + (size_t)rid * DD))[d4];
    }
}

extern "C" void kernel_launch(void* const* d_in, const int* in_sizes, int n_in,
                              void* d_out, int out_size, void* d_ws, size_t ws_size,
                              hipStream_t stream) {
    const float* x    = (const float*)d_in[0];
    const int*   ppad = (const int*)d_in[3];
    const float* nids = (const float*)d_in[4];
    const float* sw   = (const float*)d_in[5];
    const float* nd   = (const float*)d_in[6];
    const int*   subn = (const int*)d_in[7];
    const float* gum  = (const float*)d_in[8];

    int* wsi = (int*)d_ws;
    float* wsf = (float*)d_ws;

    float* out      = (float*)d_out;
    float* out_x    = out;
    float* out_nids = out + (size_t)SS * TT * DD;          // 33554432
    float* out_nm   = out_nids + TT * SS;
    float* out_pm   = out_nm + TT * SS;
    float* out_nnn  = out_pm + TT * SS;

    k_init_stats<<<1, 1024, 0, stream>>>(ppad, nids, wsi, wsf);
    k_sumexp<<<512, 256, 0, stream>>>(sw, gum, wsf + W_Z);
    k_hist<<<256, 256, 0, stream>>>(sw, gum, wsi, 0);
    k_scan<<<1, 1024, 0, stream>>>(wsi, 0);
    k_hist<<<256, 256, 0, stream>>>(sw, gum, wsi, 1);
    k_scan<<<1, 1024, 0, stream>>>(wsi, 1);
    k_hist<<<256, 256, 0, stream>>>(sw, gum, wsi, 2);
    k_scan<<<1, 1024, 0, stream>>>(wsi, 2);
    k_collect<<<256, 256, 0, stream>>>(sw, gum, wsi);
    k_finalize<<<1, 1024, 0, stream>>>(sw, gum, subn, wsi, wsf, out_nnn);
    k_small<<<(TT * SS + 255) / 256, 256, 0, stream>>>(nids, wsi, wsf, out_nids, out_nm, out_pm);
    k_x<<<SS * TT, 128, 0, stream>>>(x, nd, wsi, wsf, out_x);
}